// Round 11
// baseline (99.166 us; speedup 1.0000x reference)
//
#include <hip/hip_runtime.h>
#include <hip/hip_bf16.h>
#include <stdint.h>

#define NROW 4096
#define DIM  512
#define BM   128
#define BN   128
#define BKE  64                  // K elements per round (fp8 bytes)
#define NKT  (DIM / BKE)         // 8 rounds
#define PANEL_KT (BM * BKE)      // 8192 B staged per panel per round

typedef __attribute__((ext_vector_type(4))) float floatx4;  // MFMA 16x16 C/D

typedef const __attribute__((address_space(1))) void gvoid_t;
typedef __attribute__((address_space(3))) void       svoid_t;

// fp8 kt-major pre-swizzled layout:
//   slab (kt=k/64, G=row/8) of 8 rows x 64 B at ((kt*512+G)*8 + row%8)*64;
//   logical 8-B subchunk c (0..7) of a row sits at phys p = c ^ (row & 7).
//   -> a 128-row panel's kt-slab is 8 KB fully contiguous (staging =
//      base + tid*16, 2 instr/thread), and a frag read's 16 rows spread
//      uniformly 2 lanes/bank (free per m136).
// meta[row] = {sq_fp32, bits(y*4+ds)}.
__global__ __launch_bounds__(256) void prep_kernel(
    const float* __restrict__ X, const int* __restrict__ ds,
    const int* __restrict__ y, unsigned char* __restrict__ Xq,
    float2* __restrict__ meta, float* __restrict__ out)
{
    const int wave = threadIdx.x >> 6;
    const int lane = threadIdx.x & 63;
    const int row  = blockIdx.x * 4 + wave;
    const float4* xr = (const float4*)(X + (size_t)row * DIM);
    float4 v0 = xr[2 * lane];                    // floats 8*lane .. +3
    float4 v1 = xr[2 * lane + 1];                // floats 8*lane+4 .. +7
    float s = v0.x*v0.x + v0.y*v0.y + v0.z*v0.z + v0.w*v0.w
            + v1.x*v1.x + v1.y*v1.y + v1.z*v1.z + v1.w*v1.w;
    int q0 = __builtin_amdgcn_cvt_pk_fp8_f32(v0.x, v0.y, 0, false);
    q0     = __builtin_amdgcn_cvt_pk_fp8_f32(v0.z, v0.w, q0, true);
    int q1 = __builtin_amdgcn_cvt_pk_fp8_f32(v1.x, v1.y, 0, false);
    q1     = __builtin_amdgcn_cvt_pk_fp8_f32(v1.z, v1.w, q1, true);
    const int kt = lane >> 3;                    // k/64
    const int c  = lane & 7;                     // logical 8-B subchunk
    const int p  = c ^ (row & 7);
    *(uint2*)(Xq + ((size_t)(kt * 512 + (row >> 3)) * 8 + (row & 7)) * 64
              + p * 8) = make_uint2((unsigned)q0, (unsigned)q1);
    #pragma unroll
    for (int off = 32; off; off >>= 1) s += __shfl_xor(s, off);
    if (lane == 0)
        meta[row] = make_float2(s, __int_as_float(y[row] * 4 + ds[row]));
    if (blockIdx.x == 0 && threadIdx.x < 2) out[threadIdx.x] = 0.0f;
}

// Triangular 128x128 Gram tiles, 256 threads (4 waves 2x2, each 64x64 via
// 4x4 16x16x32 fp8 MFMAs = 0.5 LDS-reads/MFMA, the binding pipe), BKE=64
// LDS dbuf (32 KB) -> 4 blocks/CU: ALL 528 blocks co-resident, per-round
// barrier drains overlapped by 3 sibling blocks per CU.
__global__ __launch_bounds__(256, 4) void ccsa_kernel(
    const unsigned char* __restrict__ Xq, const float2* __restrict__ meta,
    const int* __restrict__ ncls, const int* __restrict__ ndom,
    float* __restrict__ out)
{
    __shared__ __align__(16) unsigned char As[2 * PANEL_KT];  // 16 KB
    __shared__ __align__(16) unsigned char Bs[2 * PANEL_KT];  // 16 KB
    __shared__ float red[8];

    // triangular decode: block t -> (bi_t <= bj_t), 528 blocks
    const int t = blockIdx.x;
    int r = (int)((sqrtf(8.0f * (float)t + 1.0f) - 1.0f) * 0.5f);
    while ((r + 1) * (r + 2) / 2 <= t) ++r;
    while (r * (r + 1) / 2 > t) --r;
    const int bj_t = r;
    const int bi_t = t - r * (r + 1) / 2;
    const bool diag = (bi_t == bj_t);
    const int bm0 = bi_t * BM;
    const int bn0 = bj_t * BN;
    const int GA = bm0 >> 3;
    const int GB = bn0 >> 3;

    const int tid    = threadIdx.x;
    const int wave   = tid >> 6;
    const int lane   = tid & 63;
    const int warp_m = wave >> 1;       // 0..1 : 64-row band
    const int warp_n = wave & 1;        // 0..1 : 64-col band
    const int m15    = lane & 15;
    const int quad   = lane >> 4;
    const int sw     = m15 & 7;         // row&7 for un-swizzle

    // j-side metadata, loop-invariant
    float sqj[4]; int yj[4], dj[4];
    #pragma unroll
    for (int tn = 0; tn < 4; ++tn) {
        const float2 mj = meta[bn0 + warp_n * 64 + tn * 16 + m15];
        sqj[tn] = mj.x;
        const int ydj = __float_as_int(mj.y);
        dj[tn] = ydj & 3; yj[tn] = ydj >> 2;
    }

    floatx4 acc[4][4];
    #pragma unroll
    for (int a = 0; a < 4; ++a)
        #pragma unroll
        for (int b = 0; b < 4; ++b)
            acc[a][b] = (floatx4){0.f, 0.f, 0.f, 0.f};

    const unsigned char* Bb = diag ? As : Bs;   // diag: A-tile == B-tile

    // staging: panel kt-slab is 8 KB contiguous; 256 thr x 2 x 16 B.
    #define STAGE(buf, kt)                                                    \
        do {                                                                  \
            const unsigned char* srcA =                                       \
                Xq + (size_t)((kt) * 512 + GA) * 512;                         \
            __builtin_amdgcn_global_load_lds(                                 \
                (gvoid_t*)(srcA + tid * 16),                                  \
                (svoid_t*)(&As[(buf) * PANEL_KT + tid * 16]), 16, 0, 0);      \
            __builtin_amdgcn_global_load_lds(                                 \
                (gvoid_t*)(srcA + 4096 + tid * 16),                           \
                (svoid_t*)(&As[(buf) * PANEL_KT + 4096 + tid * 16]),          \
                16, 0, 0);                                                    \
            if (!diag) {                                                      \
                const unsigned char* srcB =                                   \
                    Xq + (size_t)((kt) * 512 + GB) * 512;                     \
                __builtin_amdgcn_global_load_lds(                             \
                    (gvoid_t*)(srcB + tid * 16),                              \
                    (svoid_t*)(&Bs[(buf) * PANEL_KT + tid * 16]), 16, 0, 0);  \
                __builtin_amdgcn_global_load_lds(                             \
                    (gvoid_t*)(srcB + 4096 + tid * 16),                       \
                    (svoid_t*)(&Bs[(buf) * PANEL_KT + 4096 + tid * 16]),      \
                    16, 0, 0);                                                \
            }                                                                 \
        } while (0)

    // per-row LDS base offsets (slab-major): (rl/8)*512 + (rl%8)*64
    int offA[4], offB[4];
    #pragma unroll
    for (int tt = 0; tt < 4; ++tt) {
        const int rla = warp_m * 64 + tt * 16 + m15;
        const int rlb = warp_n * 64 + tt * 16 + m15;
        offA[tt] = (rla >> 3) * 512 + (rla & 7) * 64;
        offB[tt] = (rlb >> 3) * 512 + (rlb & 7) * 64;
    }

    STAGE(0, 0);
    for (int kt = 0; kt < NKT; ++kt) {
        const int cur = kt & 1;
        __syncthreads();                      // drains prev-phase loads
        if (kt + 1 < NKT) STAGE(cur ^ 1, kt + 1);
        const int cb = cur * PANEL_KT;

        #pragma unroll
        for (int s = 0; s < 2; ++s) {         // two K=32 steps per round
            const int ph = ((s * 4 + quad) ^ sw) * 8;   // un-swizzle, bytes
            long a[4], b[4];
            #pragma unroll
            for (int tt = 0; tt < 4; ++tt) {
                a[tt] = *(const long*)(&As[cb + offA[tt] + ph]);
                b[tt] = *(const long*)(&Bb[cb + offB[tt] + ph]);
            }
            #pragma unroll
            for (int tm = 0; tm < 4; ++tm)
                #pragma unroll
                for (int tn = 0; tn < 4; ++tn)
                    acc[tm][tn] = __builtin_amdgcn_mfma_f32_16x16x32_fp8_fp8(
                        a[tm], b[tn], acc[tm][tn], 0, 0, 0);
        }
    }
    #undef STAGE

    // Epilogue: C/D map col=lane&15, row=quad*4+reg (dtype-independent)
    float sa = 0.f, ss = 0.f;
    #pragma unroll
    for (int tm = 0; tm < 4; ++tm) {
        #pragma unroll
        for (int rr = 0; rr < 4; ++rr) {
            const int i = bm0 + warp_m * 64 + tm * 16 + quad * 4 + rr;
            const float2 mi = meta[i];
            const int ydi = __float_as_int(mi.y);
            const int di = ydi & 3, yi = ydi >> 2;
            #pragma unroll
            for (int tn = 0; tn < 4; ++tn) {
                if (diag) {
                    if (di < dj[tn]) {
                        const float d2   = mi.x + sqj[tn] - 2.0f * acc[tm][tn][rr];
                        const float dist = sqrtf(fmaxf(d2, 0.f));
                        if (yi == yj[tn])     sa += dist;
                        else if (yi < yj[tn]) ss += fmaxf(0.f, 1.f - dist);
                    }
                } else {
                    // fold both orientations (dist symmetric; exactly one
                    // orientation has d_lt when ds differ)
                    if (di != dj[tn]) {
                        const float d2   = mi.x + sqj[tn] - 2.0f * acc[tm][tn][rr];
                        const float dist = sqrtf(fmaxf(d2, 0.f));
                        if (yi == yj[tn]) {
                            sa += dist;
                        } else {
                            const bool take = (di < dj[tn]) ? (yi < yj[tn])
                                                            : (yj[tn] < yi);
                            if (take) ss += fmaxf(0.f, 1.f - dist);
                        }
                    }
                }
            }
        }
    }
    #pragma unroll
    for (int off = 32; off; off >>= 1) {
        sa += __shfl_xor(sa, off);
        ss += __shfl_xor(ss, off);
    }
    if (lane == 0) { red[wave] = sa; red[4 + wave] = ss; }
    __syncthreads();
    if (tid == 0) {
        const float tsa = red[0] + red[1] + red[2] + red[3];
        const float tss = red[4] + red[5] + red[6] + red[7];
        const int nc = *ncls, nd = *ndom;
        const float n_sa = (float)(nc * (nd * (nd - 1) / 2));
        const float n_s  = (float)((nc * (nc - 1) / 2) * (nd * (nd - 1) / 2));
        atomicAdd(out + 0, tsa * 0.5f / n_sa);
        atomicAdd(out + 1, tss * 0.5f / n_s);
    }
}

extern "C" void kernel_launch(void* const* d_in, const int* in_sizes, int n_in,
                              void* d_out, int out_size, void* d_ws, size_t ws_size,
                              hipStream_t stream) {
    (void)in_sizes; (void)n_in; (void)out_size; (void)ws_size;
    const float* X  = (const float*)d_in[0];
    const int*   ds = (const int*)d_in[1];
    const int*   y  = (const int*)d_in[2];
    const int*   nc = (const int*)d_in[3];
    const int*   nd = (const int*)d_in[4];
    float* out = (float*)d_out;

    unsigned char* Xq = (unsigned char*)d_ws;                          // 2 MB
    float2* meta = (float2*)((char*)d_ws + (size_t)NROW * DIM);        // 32 KB

    prep_kernel<<<NROW / 4, 256, 0, stream>>>(X, ds, y, Xq, meta, out);
    const int ntiles = NROW / BM;                                      // 32
    const int nblocks = ntiles * (ntiles + 1) / 2;                     // 528
    ccsa_kernel<<<nblocks, 256, 0, stream>>>(Xq, meta, nc, nd, out);
}